// Round 1
// baseline (1148.293 us; speedup 1.0000x reference)
//
#include <hip/hip_runtime.h>

// Drifter: B=1048576 trajectories, T=101 (t = 0,20,...,2000), FS_ORDER=8.
// x_{n+1} = x_n + (sum_f sin(f x)sw[f] + cos(f x)cw[f]) * 20
// Outputs (concatenated): t_mesh [B,101], xt [B,101] (wrapped to (-pi,pi]).
// t_sample is unused by the reference outputs.

#define B_TOTAL   1048576
#define T_STEPS   101
#define FS        8
#define DT_F      20.0f
#define CHUNK     32
#define LDSTR     (CHUNK + 1)   // +1 pad: stride 33 == 1 mod 32 -> conflict-free
#define PI_F      3.14159265358979323846f
#define TWO_PI_F  6.28318530717958647692f
#define INV_2PI_F 0.15915494309189533577f

__global__ __launch_bounds__(256) void drifter_kernel(
    const float* __restrict__ x0,
    const float* __restrict__ sw,
    const float* __restrict__ cw,
    float* __restrict__ out_tmesh,
    float* __restrict__ out_xt)
{
    __shared__ float lds[256 * LDSTR];

    const int tid = threadIdx.x;
    const int b   = blockIdx.x * 256 + tid;

    float x = x0[b];

    // weights: wave-uniform constant-index loads -> scalar loads, once
    float swr[FS], cwr[FS];
#pragma unroll
    for (int f = 0; f < FS; ++f) { swr[f] = sw[f]; cwr[f] = cw[f]; }

    const long long rowbase = (long long)blockIdx.x * 256 * T_STEPS;

#pragma unroll
    for (int chunk = 0; chunk < 4; ++chunk) {
        const int cbase = chunk * CHUNK;
        const int csize = (T_STEPS - cbase) < CHUNK ? (T_STEPS - cbase) : CHUNK;

        // ---- compute csize trajectory values into LDS ----
        for (int c = 0; c < csize; ++c) {
            // store wrapped x at global time index j = cbase + c
            float v = x + PI_F;
            // JAX/numpy mod semantics: result in [0, 2pi)
            float w = v - floorf(v * INV_2PI_F) * TWO_PI_F - PI_F;
            lds[tid * LDSTR + c] = w;

            if (cbase + c < T_STEPS - 1) {       // 100 Euler steps total
                float s1 = __sinf(x);
                float c1 = __cosf(x);
                float tc = 2.0f * c1;
                // f=0: sin term 0, cos term cw[0]
                float acc  = cwr[0] + s1 * swr[1] + c1 * cwr[1];
                float skm1 = 0.0f, ckm1 = 1.0f;  // k=0
                float sk = s1, ck = c1;          // k=1
#pragma unroll
                for (int f = 2; f < FS; ++f) {   // Chebyshev recurrence
                    float sn = tc * sk - skm1;
                    float cn = tc * ck - ckm1;
                    skm1 = sk; ckm1 = ck;
                    sk = sn;   ck = cn;
                    acc += sn * swr[f] + cn * cwr[f];
                }
                x += acc * DT_F;
            }
        }
        __syncthreads();

        // ---- coalesced transpose writeback ----
        // wave lanes 0..31 -> 32 consecutive t-columns of row r0,
        // lanes 32..63 -> row r0+1: 2 x 128B contiguous segments per store.
        {
            const int c  = tid & 31;
            const int r0 = tid >> 5;
            const float tval = DT_F * (float)(cbase + c);
            for (int it = 0; it < 32; ++it) {
                const int r = r0 + (it << 3);
                if (c < csize) {
                    const long long o = rowbase + (long long)r * T_STEPS + cbase + c;
                    out_xt[o]    = lds[r * LDSTR + c];
                    out_tmesh[o] = tval;
                }
            }
        }
        __syncthreads();
    }
}

extern "C" void kernel_launch(void* const* d_in, const int* in_sizes, int n_in,
                              void* d_out, int out_size, void* d_ws, size_t ws_size,
                              hipStream_t stream) {
    const float* x0 = (const float*)d_in[0];   // [B] fp32
    const float* sw = (const float*)d_in[1];   // [8] fp32
    const float* cw = (const float*)d_in[2];   // [8] fp32
    // d_in[3] = t_sample (int32) -- unused by reference outputs

    float* out = (float*)d_out;
    const long long half = (long long)B_TOTAL * T_STEPS;  // t_mesh first, xt second

    drifter_kernel<<<B_TOTAL / 256, 256, 0, stream>>>(x0, sw, cw, out, out + half);
}